// Round 3
// 400.341 us; speedup vs baseline: 1.0997x; 1.0997x over previous
//
#include <hip/hip_runtime.h>

#define RADIUS 0.05f
#define TH     3.0f      // N(0,1) tail: per-batch mean ~1350 hits, per-block(64K elems) mean ~84
#define SBUF   256       // per-scan-block staging cap (mean 84, +18 sigma margin)
#define SORTN  2048      // per-batch candidate cap (mean 1350, sigma 37 -> +18 sigma margin)
#define TOPC   128       // gathered top-candidate cap (K=64 + tie margin)

typedef unsigned long long u64;

__device__ __forceinline__ unsigned fkey(float f) {
  unsigned u = __float_as_uint(f);
  return (u & 0x80000000u) ? ~u : (u | 0x80000000u);  // monotonic float->uint
}

// Each (batch, g) block owns cnt slot b*16+g and buf segment (b*16+g)*bcapblk.
// Plain stores, written exactly once per launch -> no zeroing kernel, no global atomics.
__global__ __launch_bounds__(256) void scan_collect(
    const float* __restrict__ hm, unsigned* __restrict__ cnt,
    u64* __restrict__ buf, int bcapblk, int elems, int chunk) {
  const int b   = blockIdx.y;
  const int g   = blockIdx.x;
  const int tid = threadIdx.x;
  const int vbase = g * chunk;                          // in float4 units
  const float4* p = (const float4*)(hm + (size_t)b * elems) + vbase;

  __shared__ u64 sbuf[SBUF];
  __shared__ unsigned sh;
  if (tid == 0) sh = 0u;
  __syncthreads();

  auto push = [&](float v, int idx) {
    if (v > TH) {                                       // v>3 => positive => fkey = u|signbit
      unsigned pos = atomicAdd(&sh, 1u);                // LDS atomic: cheap, no XCD traffic
      if (pos < SBUF)
        sbuf[pos] = ((u64)(__float_as_uint(v) | 0x80000000u) << 32) | (unsigned)(~idx);
    }
  };

  int chunkMain = chunk & ~1023;                        // 4 float4 loads in flight per thread
  for (int i = tid; i < chunkMain; i += 1024) {
    float4 v0 = p[i], v1 = p[i + 256], v2 = p[i + 512], v3 = p[i + 768];
    int g0 = (vbase + i) << 2, g1 = (vbase + i + 256) << 2;
    int g2 = (vbase + i + 512) << 2, g3 = (vbase + i + 768) << 2;
    push(v0.x, g0); push(v0.y, g0 + 1); push(v0.z, g0 + 2); push(v0.w, g0 + 3);
    push(v1.x, g1); push(v1.y, g1 + 1); push(v1.z, g1 + 2); push(v1.w, g1 + 3);
    push(v2.x, g2); push(v2.y, g2 + 1); push(v2.z, g2 + 2); push(v2.w, g2 + 3);
    push(v3.x, g3); push(v3.y, g3 + 1); push(v3.z, g3 + 2); push(v3.w, g3 + 3);
  }
  for (int i = chunkMain + tid; i < chunk; i += 256) {  // tail (empty for 1024x1024)
    float4 v = p[i];
    int gg = (vbase + i) << 2;
    push(v.x, gg); push(v.y, gg + 1); push(v.z, gg + 2); push(v.w, gg + 3);
  }

  __syncthreads();
  unsigned h = sh;
  unsigned cap = (unsigned)bcapblk; if (cap > (unsigned)SBUF) cap = SBUF;
  unsigned stored = h < cap ? h : cap;
  u64* dst = buf + (size_t)(b * 16 + g) * (size_t)bcapblk;
  for (unsigned i = tid; i < stored; i += 256) dst[i] = sbuf[i];
  if (tid == 0)
    cnt[b * 16 + g] = stored | (h > stored ? 0x80000000u : 0u);  // bit31 = overflow
}

__global__ __launch_bounds__(256) void select_k(
    const float* __restrict__ hm, const unsigned* __restrict__ cnt,
    const u64* __restrict__ buf, int bcapblk,
    float* __restrict__ out, int W, int H, int K, int nk, int elems) {
  const int b = blockIdx.x, tid = threadIdx.x;

  __shared__ u64 s[SORTN];          // packed candidates (val fkey | ~idx)
  __shared__ unsigned skey[SORTN];  // value keys only (halves LDS traffic in search)
  __shared__ u64 top[TOPC];
  __shared__ unsigned segoff[17];
  __shared__ int s_good, s_m;
  __shared__ unsigned s_cnt;
  __shared__ float topx[64], topy[64];
  __shared__ float outbuf[128];

  if (tid == 0) {
    unsigned tot = 0; int ok = (bcapblk > 0);
    for (int g = 0; g < 16; g++) {
      unsigned cv = (bcapblk > 0) ? cnt[b * 16 + g] : 0u;
      segoff[g] = tot;
      if (cv & 0x80000000u) ok = 0;
      tot += (cv & 0x7FFFFFFFu);
    }
    segoff[16] = tot;
    s_good = ok && tot >= (unsigned)K && tot <= (unsigned)SORTN;
    s_m = 0;
  }
  __syncthreads();
  const int good = s_good;
  const unsigned c = segoff[16];

  if (good) {
    // gather 16 per-block segments into contiguous LDS
    for (int g = 0; g < 16; g++) {
      unsigned off = segoff[g], len = segoff[g + 1] - off;
      const u64* src = buf + (size_t)(b * 16 + g) * (size_t)bcapblk;
      for (unsigned i = tid; i < len; i += 256) {
        u64 e = src[i];
        s[off + i] = e;
        skey[off + i] = (unsigned)(e >> 32);
      }
    }
    __syncthreads();

    // binary search the K-th largest 32-bit value key over LDS-resident keys
    // (same barrier structure as the round-0-proven fallback search)
    unsigned lo = 0xC0400000u;      // fkey(TH): every stored key >= this
    unsigned hi = 0xFFFFFFFFu;
    while (lo < hi) {
      unsigned mid = lo + ((hi - lo) >> 1) + 1u;
      if (tid == 0) s_cnt = 0u;
      __syncthreads();
      unsigned local = 0;
      for (unsigned i = tid; i < c; i += 256) local += (skey[i] >= mid);
      #pragma unroll
      for (int o = 32; o > 0; o >>= 1) local += __shfl_xor(local, o);
      if ((tid & 63) == 0) atomicAdd(&s_cnt, local);
      __syncthreads();
      unsigned tot = s_cnt;
      if (tot >= (unsigned)K) lo = mid; else hi = mid - 1u;
      __syncthreads();                    // protect s_cnt re-zero next iteration
    }

    // gather all candidates >= threshold (K <= m <= K+ties; ties >64 impossible in practice)
    for (unsigned i = tid; i < c; i += 256) {
      if (skey[i] >= lo) {
        int p = atomicAdd(&s_m, 1);
        if (p < TOPC) top[p] = s[i];
      }
    }
    __syncthreads();
  } else {
    // ---- exact data-agnostic fallback: binary search K-th key over whole image ----
    unsigned lo = 0u, hi = 0xFFFFFFFFu;
    const float4* p4 = (const float4*)(hm + (size_t)b * elems);
    const int nvec4 = elems >> 2;
    while (lo < hi) {
      unsigned mid = lo + ((hi - lo) >> 1) + 1u;
      if (tid == 0) s_cnt = 0u;
      __syncthreads();
      unsigned local = 0;
      for (int i = tid; i < nvec4; i += 256) {
        float4 v = p4[i];
        local += (fkey(v.x) >= mid) + (fkey(v.y) >= mid) + (fkey(v.z) >= mid) + (fkey(v.w) >= mid);
      }
      #pragma unroll
      for (int o = 32; o > 0; o >>= 1) local += __shfl_xor(local, o);
      if ((tid & 63) == 0) atomicAdd(&s_cnt, local);
      __syncthreads();
      if (s_cnt >= (unsigned)K) lo = mid; else hi = mid - 1u;
      __syncthreads();                    // protect s_cnt re-zero next iteration
    }
    const float* q = hm + (size_t)b * elems;
    for (int i = tid; i < elems; i += 256) {
      unsigned kk = fkey(q[i]);
      if (kk >= lo) {
        int p = atomicAdd(&s_m, 1);
        if (p < TOPC) top[p] = ((u64)kk << 32) | (unsigned)(~i);
      }
    }
    __syncthreads();
  }

  // ---- pad + bitonic sort TOPC=128 descending on packed (fkey | ~idx) ----
  int m = s_m; if (m > TOPC) m = TOPC;
  for (int i = tid; i < TOPC; i += 256) if (i >= m) top[i] = 0ull;
  __syncthreads();
  for (int k2 = 2; k2 <= TOPC; k2 <<= 1) {
    for (int j = k2 >> 1; j > 0; j >>= 1) {
      if (tid < TOPC) {
        int ix = tid ^ j;
        if (ix > tid) {
          u64 a = top[tid], bb = top[ix];
          bool desc = ((tid & k2) == 0);
          if (desc ? (a < bb) : (a > bb)) { top[tid] = bb; top[ix] = a; }
        }
      }
      __syncthreads();
    }
  }

  // ---- decode top-K coords ----
  const float invW = 1.0f / (float)(W - 1);
  const float invH = 1.0f / (float)(H - 1);
  if (tid < K) {
    u64 e = top[tid];
    int idx = (int)(~(unsigned)(e & 0xFFFFFFFFu));
    int ty = idx / W;
    int tx = idx - ty * W;
    topx[tid] = (float)tx * invW;
    topy[tid] = (float)ty * invH;
  }
  for (int i = tid; i < 2 * nk; i += 256) outbuf[i] = 0.0f;
  __syncthreads();

  // ---- single-wave greedy NMS (K <= 64): ballot/shfl, zero barriers ----
  if (tid < 64) {
    float myx = (tid < K) ? topx[tid] : 0.0f;
    float myy = (tid < K) ? topy[tid] : 0.0f;
    bool sel = false;
    int cntA = 0;
    for (int i = 0; i < K; i++) {
      float xi = __shfl(myx, i);
      float yi = __shfl(myy, i);
      float dx = myx - xi, dy = myy - yi;
      bool close = sel && (sqrtf(dx * dx + dy * dy) < RADIUS);
      u64 anym = __ballot(close);
      bool accept = (anym == 0ull) && (cntA < nk);
      if (tid == i) sel = accept;
      cntA += accept ? 1 : 0;
    }
    u64 selball = __ballot(sel);
    if (sel) {
      int slot = __popcll(selball & ((1ull << tid) - 1ull));  // score-order compaction
      if (slot < nk) { outbuf[2 * slot] = myx; outbuf[2 * slot + 1] = myy; }
    }
  }
  __syncthreads();

  float* outp = out + (size_t)b * 2 * nk;
  for (int i = tid; i < 2 * nk; i += 256) outp[i] = outbuf[i];
}

extern "C" void kernel_launch(void* const* d_in, const int* in_sizes, int n_in,
                              void* d_out, int out_size, void* d_ws, size_t ws_size,
                              hipStream_t stream) {
  const float* hm = (const float*)d_in[0];
  const int H = 1024, W = 1024;
  const int elems = H * W;
  int B = in_sizes[0] / elems;              // 64
  int nk = out_size / (B * 2);              // 16
  int K = 4 * nk;                           // 64
  if (K > elems) K = elems;
  if (K > 64) K = 64;                       // single-wave NMS bound (problem: K=64)

  // ws layout: cnt B*16 u32 | buf (B*16)*bcapblk u64  (no zeroing needed: plain stores)
  unsigned* cnt = (unsigned*)d_ws;
  size_t off_buf = ((size_t)B * 16 * sizeof(unsigned) + 255) & ~(size_t)255;
  u64* buf = (u64*)((char*)d_ws + off_buf);
  int bcapblk = 0;
  if (ws_size > off_buf) {
    size_t avail = ws_size - off_buf;
    long long capl = (long long)(avail / ((size_t)B * 16 * sizeof(u64)));
    bcapblk = (capl > SBUF) ? SBUF : (int)capl;
    if (bcapblk < 16) bcapblk = 0;          // too small to be useful -> exact fallback
  }

  if (bcapblk > 0) {
    const int gx = 16;
    int chunk = (elems >> 2) / gx;          // 16384 float4 per block
    dim3 grid(gx, B);
    scan_collect<<<grid, 256, 0, stream>>>(hm, cnt, buf, bcapblk, elems, chunk);
  }
  select_k<<<B, 256, 0, stream>>>(hm, cnt, buf, bcapblk, (float*)d_out, W, H, K, nk, elems);
}

// Round 4
// 370.516 us; speedup vs baseline: 1.1882x; 1.0805x over previous
//
#include <hip/hip_runtime.h>

#define RADIUS 0.05f
#define TH     3.0f      // N(0,1) tail: per-batch mean ~1350 hits, per-block(64K elems) mean ~84
#define SBUF   256       // per-scan-block staging cap (mean 84, +18 sigma margin)
#define SORTN  2048      // per-batch candidate cap (mean 1350, sigma 37 -> +18 sigma margin)
#define TOPC   128       // gathered top-candidate cap (K=64 + tie margin)

typedef unsigned long long u64;
typedef float __attribute__((ext_vector_type(4))) f4;

__device__ __forceinline__ unsigned fkey(float f) {
  unsigned u = __float_as_uint(f);
  return (u & 0x80000000u) ? ~u : (u | 0x80000000u);  // monotonic float->uint
}

// Each (batch, g) block owns cnt slot b*16+g and buf segment (b*16+g)*bcapblk.
// Plain stores, written exactly once per launch -> no zeroing kernel, no global atomics.
__global__ __launch_bounds__(256) void scan_collect(
    const float* __restrict__ hm, unsigned* __restrict__ cnt,
    u64* __restrict__ buf, int bcapblk, int elems, int chunk) {
  const int b   = blockIdx.y;
  const int g   = blockIdx.x;
  const int tid = threadIdx.x;
  const int vbase = g * chunk;                          // in float4 units
  const f4* p = (const f4*)(hm + (size_t)b * elems) + vbase;

  __shared__ u64 sbuf[SBUF];
  __shared__ unsigned sh;
  if (tid == 0) sh = 0u;
  __syncthreads();

  auto push = [&](float v, int idx) {
    if (v > TH) {                                       // v>3 => positive => fkey = u|signbit
      unsigned pos = atomicAdd(&sh, 1u);                // LDS atomic: cheap, no XCD traffic
      if (pos < SBUF)
        sbuf[pos] = ((u64)(__float_as_uint(v) | 0x80000000u) << 32) | (unsigned)(~idx);
    }
  };

  // 8 nontemporal float4 loads in flight per thread (read-once stream: skip L2 alloc)
  int chunkMain = chunk & ~2047;
  for (int i = tid; i < chunkMain; i += 2048) {
    f4 v0 = __builtin_nontemporal_load(p + i);
    f4 v1 = __builtin_nontemporal_load(p + i + 256);
    f4 v2 = __builtin_nontemporal_load(p + i + 512);
    f4 v3 = __builtin_nontemporal_load(p + i + 768);
    f4 v4 = __builtin_nontemporal_load(p + i + 1024);
    f4 v5 = __builtin_nontemporal_load(p + i + 1280);
    f4 v6 = __builtin_nontemporal_load(p + i + 1536);
    f4 v7 = __builtin_nontemporal_load(p + i + 1792);
    int g0 = (vbase + i) << 2;
    push(v0.x, g0);        push(v0.y, g0 + 1);    push(v0.z, g0 + 2);    push(v0.w, g0 + 3);
    push(v1.x, g0 + 1024); push(v1.y, g0 + 1025); push(v1.z, g0 + 1026); push(v1.w, g0 + 1027);
    push(v2.x, g0 + 2048); push(v2.y, g0 + 2049); push(v2.z, g0 + 2050); push(v2.w, g0 + 2051);
    push(v3.x, g0 + 3072); push(v3.y, g0 + 3073); push(v3.z, g0 + 3074); push(v3.w, g0 + 3075);
    push(v4.x, g0 + 4096); push(v4.y, g0 + 4097); push(v4.z, g0 + 4098); push(v4.w, g0 + 4099);
    push(v5.x, g0 + 5120); push(v5.y, g0 + 5121); push(v5.z, g0 + 5122); push(v5.w, g0 + 5123);
    push(v6.x, g0 + 6144); push(v6.y, g0 + 6145); push(v6.z, g0 + 6146); push(v6.w, g0 + 6147);
    push(v7.x, g0 + 7168); push(v7.y, g0 + 7169); push(v7.z, g0 + 7170); push(v7.w, g0 + 7171);
  }
  for (int i = chunkMain + tid; i < chunk; i += 256) {  // tail (empty for 1024x1024)
    f4 v = __builtin_nontemporal_load(p + i);
    int gg = (vbase + i) << 2;
    push(v.x, gg); push(v.y, gg + 1); push(v.z, gg + 2); push(v.w, gg + 3);
  }

  __syncthreads();
  unsigned h = sh;
  unsigned cap = (unsigned)bcapblk; if (cap > (unsigned)SBUF) cap = SBUF;
  unsigned stored = h < cap ? h : cap;
  u64* dst = buf + (size_t)(b * 16 + g) * (size_t)bcapblk;
  for (unsigned i = tid; i < stored; i += 256) dst[i] = sbuf[i];
  if (tid == 0)
    cnt[b * 16 + g] = stored | (h > stored ? 0x80000000u : 0u);  // bit31 = overflow
}

__global__ __launch_bounds__(256) void select_k(
    const float* __restrict__ hm, const unsigned* __restrict__ cnt,
    const u64* __restrict__ buf, int bcapblk,
    float* __restrict__ out, int W, int H, int K, int nk, int elems) {
  const int b = blockIdx.x, tid = threadIdx.x;

  __shared__ unsigned skey[SORTN];  // candidate value keys (SoA: halves LDS traffic)
  __shared__ unsigned sidx[SORTN];  // candidate packed ~idx
  __shared__ u64 top[TOPC];
  __shared__ unsigned segoff[17];
  __shared__ int s_good, s_m;
  __shared__ unsigned s_acc[2];     // double-buffered monotone count accumulators
  __shared__ unsigned s_kmin, s_kmax;
  __shared__ unsigned s_cnt;        // fallback-path accumulator
  __shared__ float topx[64], topy[64];
  __shared__ float outbuf[128];

  if (tid == 0) {
    unsigned tot = 0; int ok = (bcapblk > 0);
    for (int g = 0; g < 16; g++) {
      unsigned cv = (bcapblk > 0) ? cnt[b * 16 + g] : 0u;
      segoff[g] = tot;
      if (cv & 0x80000000u) ok = 0;
      tot += (cv & 0x7FFFFFFFu);
    }
    segoff[16] = tot;
    s_good = ok && tot >= (unsigned)K && tot <= (unsigned)SORTN;
    s_m = 0;
    s_acc[0] = 0u; s_acc[1] = 0u;
    s_kmin = 0xFFFFFFFFu; s_kmax = 0u;
  }
  __syncthreads();
  const int good = s_good;
  const unsigned c = segoff[16];

  if (good) {
    // gather 16 per-block segments into contiguous LDS (SoA), tracking min/max key
    unsigned lkmin = 0xFFFFFFFFu, lkmax = 0u;
    for (int g = 0; g < 16; g++) {
      unsigned off = segoff[g], len = segoff[g + 1] - off;
      const u64* src = buf + (size_t)(b * 16 + g) * (size_t)bcapblk;
      for (unsigned i = tid; i < len; i += 256) {
        u64 e = src[i];
        unsigned k32 = (unsigned)(e >> 32);
        skey[off + i] = k32;
        sidx[off + i] = (unsigned)(e & 0xFFFFFFFFu);
        lkmin = lkmin < k32 ? lkmin : k32;
        lkmax = lkmax > k32 ? lkmax : k32;
      }
    }
    #pragma unroll
    for (int o = 32; o > 0; o >>= 1) {
      unsigned a = __shfl_xor(lkmin, o); lkmin = lkmin < a ? lkmin : a;
      unsigned bx = __shfl_xor(lkmax, o); lkmax = lkmax > bx ? lkmax : bx;
    }
    if ((tid & 63) == 0) { atomicMin(&s_kmin, lkmin); atomicMax(&s_kmax, lkmax); }
    __syncthreads();

    // exact binary search for the K-th largest key over [kmin, kmax]:
    // ~23 iters, ONE barrier each. Double-buffered monotone accumulator:
    // iter it adds into s_acc[it&1]; every thread tracks the previous total of
    // that buffer in a register (base0/base1) and subtracts -> no re-zero pass.
    // Next iter's adds target the other buffer, so post-barrier reads of this
    // buffer are protected until the next barrier.
    unsigned lo = s_kmin, hi = s_kmax;
    // invariants: count(>=lo)=c>=K (lo=min key), count(>=hi+1)=0<K (hi=max key)
    unsigned base0 = 0u, base1 = 0u;
    int it = 0;
    while (lo < hi) {
      unsigned mid = lo + ((hi - lo) >> 1) + 1u;
      unsigned local = 0;
      for (unsigned i = tid; i < c; i += 256) local += (skey[i] >= mid);
      #pragma unroll
      for (int o = 32; o > 0; o >>= 1) local += __shfl_xor(local, o);
      if ((tid & 63) == 0) atomicAdd(&s_acc[it & 1], local);
      __syncthreads();
      unsigned acc = s_acc[it & 1];
      unsigned tot = acc - ((it & 1) ? base1 : base0);
      if (it & 1) base1 = acc; else base0 = acc;
      if (tot >= (unsigned)K) lo = mid; else hi = mid - 1u;
      it++;
    }

    // gather all candidates >= threshold (K <= m <= K+ties; ties >64 impossible in practice)
    for (unsigned i = tid; i < c; i += 256) {
      if (skey[i] >= lo) {
        int p = atomicAdd(&s_m, 1);
        if (p < TOPC) top[p] = ((u64)skey[i] << 32) | sidx[i];
      }
    }
    __syncthreads();
  } else {
    // ---- exact data-agnostic fallback: binary search K-th key over whole image ----
    unsigned lo = 0u, hi = 0xFFFFFFFFu;
    const float4* p4 = (const float4*)(hm + (size_t)b * elems);
    const int nvec4 = elems >> 2;
    while (lo < hi) {
      unsigned mid = lo + ((hi - lo) >> 1) + 1u;
      if (tid == 0) s_cnt = 0u;
      __syncthreads();
      unsigned local = 0;
      for (int i = tid; i < nvec4; i += 256) {
        float4 v = p4[i];
        local += (fkey(v.x) >= mid) + (fkey(v.y) >= mid) + (fkey(v.z) >= mid) + (fkey(v.w) >= mid);
      }
      #pragma unroll
      for (int o = 32; o > 0; o >>= 1) local += __shfl_xor(local, o);
      if ((tid & 63) == 0) atomicAdd(&s_cnt, local);
      __syncthreads();
      if (s_cnt >= (unsigned)K) lo = mid; else hi = mid - 1u;
      __syncthreads();                    // protect s_cnt re-zero next iteration
    }
    const float* q = hm + (size_t)b * elems;
    for (int i = tid; i < elems; i += 256) {
      unsigned kk = fkey(q[i]);
      if (kk >= lo) {
        int p = atomicAdd(&s_m, 1);
        if (p < TOPC) top[p] = ((u64)kk << 32) | (unsigned)(~i);
      }
    }
    __syncthreads();
  }

  // ---- pad + bitonic sort TOPC=128 descending on packed (fkey | ~idx) ----
  int m = s_m; if (m > TOPC) m = TOPC;
  for (int i = tid; i < TOPC; i += 256) if (i >= m) top[i] = 0ull;
  __syncthreads();
  for (int k2 = 2; k2 <= TOPC; k2 <<= 1) {
    for (int j = k2 >> 1; j > 0; j >>= 1) {
      if (tid < TOPC) {
        int ix = tid ^ j;
        if (ix > tid) {
          u64 a = top[tid], bb = top[ix];
          bool desc = ((tid & k2) == 0);
          if (desc ? (a < bb) : (a > bb)) { top[tid] = bb; top[ix] = a; }
        }
      }
      __syncthreads();
    }
  }

  // ---- decode top-K coords ----
  const float invW = 1.0f / (float)(W - 1);
  const float invH = 1.0f / (float)(H - 1);
  if (tid < K) {
    u64 e = top[tid];
    int idx = (int)(~(unsigned)(e & 0xFFFFFFFFu));
    int ty = idx / W;
    int tx = idx - ty * W;
    topx[tid] = (float)tx * invW;
    topy[tid] = (float)ty * invH;
  }
  for (int i = tid; i < 2 * nk; i += 256) outbuf[i] = 0.0f;
  __syncthreads();

  // ---- single-wave greedy NMS (K <= 64): ballot/shfl, zero barriers ----
  if (tid < 64) {
    float myx = (tid < K) ? topx[tid] : 0.0f;
    float myy = (tid < K) ? topy[tid] : 0.0f;
    bool sel = false;
    int cntA = 0;
    for (int i = 0; i < K; i++) {
      float xi = __shfl(myx, i);
      float yi = __shfl(myy, i);
      float dx = myx - xi, dy = myy - yi;
      bool close = sel && (sqrtf(dx * dx + dy * dy) < RADIUS);
      u64 anym = __ballot(close);
      bool accept = (anym == 0ull) && (cntA < nk);
      if (tid == i) sel = accept;
      cntA += accept ? 1 : 0;
    }
    u64 selball = __ballot(sel);
    if (sel) {
      int slot = __popcll(selball & ((1ull << tid) - 1ull));  // score-order compaction
      if (slot < nk) { outbuf[2 * slot] = myx; outbuf[2 * slot + 1] = myy; }
    }
  }
  __syncthreads();

  float* outp = out + (size_t)b * 2 * nk;
  for (int i = tid; i < 2 * nk; i += 256) outp[i] = outbuf[i];
}

extern "C" void kernel_launch(void* const* d_in, const int* in_sizes, int n_in,
                              void* d_out, int out_size, void* d_ws, size_t ws_size,
                              hipStream_t stream) {
  const float* hm = (const float*)d_in[0];
  const int H = 1024, W = 1024;
  const int elems = H * W;
  int B = in_sizes[0] / elems;              // 64
  int nk = out_size / (B * 2);              // 16
  int K = 4 * nk;                           // 64
  if (K > elems) K = elems;
  if (K > 64) K = 64;                       // single-wave NMS bound (problem: K=64)

  // ws layout: cnt B*16 u32 | buf (B*16)*bcapblk u64  (no zeroing needed: plain stores)
  unsigned* cnt = (unsigned*)d_ws;
  size_t off_buf = ((size_t)B * 16 * sizeof(unsigned) + 255) & ~(size_t)255;
  u64* buf = (u64*)((char*)d_ws + off_buf);
  int bcapblk = 0;
  if (ws_size > off_buf) {
    size_t avail = ws_size - off_buf;
    long long capl = (long long)(avail / ((size_t)B * 16 * sizeof(u64)));
    bcapblk = (capl > SBUF) ? SBUF : (int)capl;
    if (bcapblk < 16) bcapblk = 0;          // too small to be useful -> exact fallback
  }

  if (bcapblk > 0) {
    const int gx = 16;
    int chunk = (elems >> 2) / gx;          // 16384 float4 per block
    dim3 grid(gx, B);
    scan_collect<<<grid, 256, 0, stream>>>(hm, cnt, buf, bcapblk, elems, chunk);
  }
  select_k<<<B, 256, 0, stream>>>(hm, cnt, buf, bcapblk, (float*)d_out, W, H, K, nk, elems);
}